// Round 2
// baseline (317.679 us; speedup 1.0000x reference)
//
#include <hip/hip_runtime.h>
#include <stdint.h>
#include <stddef.h>

#define M_DIM 2048
#define N_DIM 11008
#define K_DIM 4096
#define BM 128
#define BN 128
#define BK 32

typedef __attribute__((ext_vector_type(4))) float f32x4;
typedef __attribute__((ext_vector_type(4))) float f4;
typedef __attribute__((ext_vector_type(4))) int i4;
typedef __attribute__((ext_vector_type(8))) __bf16 bf16x8;
typedef __attribute__((ext_vector_type(8))) unsigned short us8;

// round-to-nearest-even fp32 -> bf16
__device__ inline unsigned short f2bf(float f) {
  unsigned u = __builtin_bit_cast(unsigned, f);
  u += 0x7fffu + ((u >> 16) & 1u);
  return (unsigned short)(u >> 16);
}

// ---------------- conversion kernels ----------------

__global__ void __launch_bounds__(256) cvt_x_kernel(const float* __restrict__ x,
                                                    us8* __restrict__ xb, int n8) {
  int i = blockIdx.x * 256 + threadIdx.x;
  if (i >= n8) return;
  const f4* src = (const f4*)x;
  f4 a = src[2 * i];
  f4 b = src[2 * i + 1];
  us8 o;
  o[0] = f2bf(a[0]); o[1] = f2bf(a[1]); o[2] = f2bf(a[2]); o[3] = f2bf(a[3]);
  o[4] = f2bf(b[0]); o[5] = f2bf(b[1]); o[6] = f2bf(b[2]); o[7] = f2bf(b[3]);
  xb[i] = o;
}

// W_q arrives as int32 per element (harness passes integer inputs as int*).
// Each thread converts 16 ints (4x dwordx4 loads) -> 16 bf16 (2x us8 stores).
__global__ void __launch_bounds__(256) cvt_w_kernel(const int* __restrict__ w,
                                                    us8* __restrict__ wb, int n16) {
  int i = blockIdx.x * 256 + threadIdx.x;
  if (i >= n16) return;
  const i4* src = (const i4*)w + 4 * (size_t)i;
  i4 v0 = src[0], v1 = src[1], v2 = src[2], v3 = src[3];
  us8 lo, hi;
  lo[0] = f2bf((float)v0[0]); lo[1] = f2bf((float)v0[1]);
  lo[2] = f2bf((float)v0[2]); lo[3] = f2bf((float)v0[3]);
  lo[4] = f2bf((float)v1[0]); lo[5] = f2bf((float)v1[1]);
  lo[6] = f2bf((float)v1[2]); lo[7] = f2bf((float)v1[3]);
  hi[0] = f2bf((float)v2[0]); hi[1] = f2bf((float)v2[1]);
  hi[2] = f2bf((float)v2[2]); hi[3] = f2bf((float)v2[3]);
  hi[4] = f2bf((float)v3[0]); hi[5] = f2bf((float)v3[1]);
  hi[6] = f2bf((float)v3[2]); hi[7] = f2bf((float)v3[3]);
  wb[2 * (size_t)i] = lo;
  wb[2 * (size_t)i + 1] = hi;
}

// ---------------- GEMM (m97-style 128x128, bf16 MFMA) ----------------

__device__ inline void gload_lds16(const void* g, void* l) {
  __builtin_amdgcn_global_load_lds((const __attribute__((address_space(1))) void*)g,
                                   (__attribute__((address_space(3))) void*)l, 16, 0, 0);
}

__global__ void __launch_bounds__(256) gemm_bf16(
    const unsigned short* __restrict__ Xb,   // [M, K] bf16
    const unsigned short* __restrict__ Wb,   // [N, K] bf16 (B^T layout)
    const float* __restrict__ scale,         // [N]
    const float* __restrict__ bias,          // [N]
    float* __restrict__ out) {               // [M, N] fp32
  __shared__ __align__(16) unsigned short Alds[BM * BK];  // 8 KiB, row-major [128][32]
  __shared__ __align__(16) unsigned short Blds[BN * BK];  // 8 KiB

  const int tid = threadIdx.x;
  const int lane = tid & 63;
  const int wid = tid >> 6;              // 4 waves, 2x2
  const int nbn = N_DIM / BN;            // 86
  const int bm = blockIdx.x / nbn;
  const int bn = blockIdx.x % nbn;
  const int row0 = bm * BM;
  const int col0 = bn * BN;

  // staging map: thread t loads 16B at (row = t>>2, kcol = (t&3)*8); two iters cover 128 rows.
  // LDS dest for global_load_lds is wave-uniform base + lane*16 -> layout is linear in t*16.
  const int srow = tid >> 2;             // 0..63
  const int skc = (tid & 3) * 8;         // 0,8,16,24
  const unsigned short* Ag0 = Xb + (size_t)(row0 + srow) * K_DIM + skc;
  const unsigned short* Ag1 = Ag0 + (size_t)64 * K_DIM;
  const unsigned short* Bg0 = Wb + (size_t)(col0 + srow) * K_DIM + skc;
  const unsigned short* Bg1 = Bg0 + (size_t)64 * K_DIM;
  char* Al = (char*)Alds + wid * 1024;   // + lane*16 implicit
  char* Bl = (char*)Blds + wid * 1024;

  const int fr = lane & 15;
  const int fq = lane >> 4;              // 0..3
  const int wm = wid >> 1, wn = wid & 1; // wave tile: 64x64

  f32x4 acc[4][4] = {};

  for (int k0 = 0; k0 < K_DIM; k0 += BK) {
    gload_lds16(Ag0 + k0, Al);
    gload_lds16(Ag1 + k0, Al + 4096);
    gload_lds16(Bg0 + k0, Bl);
    gload_lds16(Bg1 + k0, Bl + 4096);
    __syncthreads();

    bf16x8 a[4], b[4];
#pragma unroll
    for (int m = 0; m < 4; ++m)
      a[m] = *(const bf16x8*)&Alds[(wm * 64 + m * 16 + fr) * BK + fq * 8];
#pragma unroll
    for (int n = 0; n < 4; ++n)
      b[n] = *(const bf16x8*)&Blds[(wn * 64 + n * 16 + fr) * BK + fq * 8];

#pragma unroll
    for (int m = 0; m < 4; ++m)
#pragma unroll
      for (int n = 0; n < 4; ++n)
        acc[m][n] = __builtin_amdgcn_mfma_f32_16x16x32_bf16(a[m], b[n], acc[m][n], 0, 0, 0);

    __syncthreads();
  }

  // epilogue: C/D layout col=lane&15, row=(lane>>4)*4+j. Apply scale/bias here (fp32-exact).
#pragma unroll
  for (int n = 0; n < 4; ++n) {
    const int c = col0 + wn * 64 + n * 16 + fr;
    const float sc = scale[c];
    const float bi = bias[c];
#pragma unroll
    for (int m = 0; m < 4; ++m) {
      const int r = row0 + wm * 64 + m * 16 + fq * 4;
#pragma unroll
      for (int j = 0; j < 4; ++j)
        out[(size_t)(r + j) * N_DIM + c] = acc[m][n][j] * sc + bi;
    }
  }
}

// ---------------- fallback (only if d_ws too small) ----------------

__global__ void __launch_bounds__(256) naive_kernel(
    const float* __restrict__ x, const int* __restrict__ w,
    const float* __restrict__ scale, const float* __restrict__ bias,
    float* __restrict__ out) {
  size_t idx = (size_t)blockIdx.x * 256 + threadIdx.x;
  if (idx >= (size_t)M_DIM * N_DIM) return;
  int m = (int)(idx / N_DIM);
  int n = (int)(idx % N_DIM);
  const float* xr = x + (size_t)m * K_DIM;
  const int* wr = w + (size_t)n * K_DIM;
  float acc = 0.f;
  for (int k = 0; k < K_DIM; k += 4) {
    f4 xv = *(const f4*)(xr + k);
    i4 wv = *(const i4*)(wr + k);
    acc += xv[0] * (float)wv[0];
    acc += xv[1] * (float)wv[1];
    acc += xv[2] * (float)wv[2];
    acc += xv[3] * (float)wv[3];
  }
  out[idx] = acc * scale[n] + bias[n];
}

// ---------------- launch ----------------

extern "C" void kernel_launch(void* const* d_in, const int* in_sizes, int n_in,
                              void* d_out, int out_size, void* d_ws, size_t ws_size,
                              hipStream_t stream) {
  const float* x = (const float*)d_in[0];
  const int* wq = (const int*)d_in[1];
  const float* scale = (const float*)d_in[2];
  const float* bias = (const float*)d_in[3];
  float* out = (float*)d_out;

  const size_t xb_bytes = (size_t)M_DIM * K_DIM * 2;   // 16.8 MB
  const size_t wb_bytes = (size_t)N_DIM * K_DIM * 2;   // 90.2 MB

  if (ws_size >= xb_bytes + wb_bytes) {
    unsigned short* xb = (unsigned short*)d_ws;
    unsigned short* wb = (unsigned short*)((char*)d_ws + xb_bytes);

    const int n8 = M_DIM * K_DIM / 8;
    cvt_x_kernel<<<(n8 + 255) / 256, 256, 0, stream>>>(x, (us8*)xb, n8);

    const int n16 = N_DIM * K_DIM / 16;
    cvt_w_kernel<<<(n16 + 255) / 256, 256, 0, stream>>>(wq, (us8*)wb, n16);

    const int grid = (M_DIM / BM) * (N_DIM / BN);  // 16 * 86 = 1376
    gemm_bf16<<<grid, 256, 0, stream>>>(xb, wb, scale, bias, out);
  } else {
    const size_t total = (size_t)M_DIM * N_DIM;
    naive_kernel<<<(unsigned)((total + 255) / 256), 256, 0, stream>>>(x, wq, scale, bias, out);
  }
}

// Round 3
// 265.015 us; speedup vs baseline: 1.1987x; 1.1987x over previous
//
#include <hip/hip_runtime.h>
#include <stdint.h>
#include <stddef.h>

#define M_DIM 2048
#define N_DIM 11008
#define K_DIM 4096
#define BM 128
#define BN 256
#define BK 64
#define NT (K_DIM / BK)   // 64
#define NBM (M_DIM / BM)  // 16
#define NBN (N_DIM / BN)  // 43
#define GRID (NBM * NBN)  // 688 (divisible by 8 -> simple XCD swizzle valid)

typedef __attribute__((ext_vector_type(4))) float f32x4;
typedef __attribute__((ext_vector_type(4))) float f4;
typedef __attribute__((ext_vector_type(4))) int i4;
typedef __attribute__((ext_vector_type(8))) __bf16 bf16x8;
typedef __attribute__((ext_vector_type(8))) unsigned short us8;

#define VMCNT6() asm volatile("s_waitcnt vmcnt(6)" ::: "memory")
#define VMCNT2() asm volatile("s_waitcnt vmcnt(2)" ::: "memory")
#define VMCNT0() asm volatile("s_waitcnt vmcnt(0)" ::: "memory")
#define FENCE() asm volatile("" ::: "memory")
#define BARRIER()                 \
  do {                            \
    FENCE();                      \
    __builtin_amdgcn_s_barrier(); \
    FENCE();                      \
  } while (0)

// round-to-nearest-even fp32 -> bf16
__device__ inline unsigned short f2bf(float f) {
  unsigned u = __builtin_bit_cast(unsigned, f);
  u += 0x7fffu + ((u >> 16) & 1u);
  return (unsigned short)(u >> 16);
}

__device__ inline void gload_lds16(const void* g, void* l) {
  __builtin_amdgcn_global_load_lds((const __attribute__((address_space(1))) void*)g,
                                   (__attribute__((address_space(3))) void*)l, 16, 0, 0);
}

// ---------------- conversion kernels ----------------

__global__ void __launch_bounds__(256) cvt_x_kernel(const float* __restrict__ x,
                                                    us8* __restrict__ xb, int n8) {
  int i = blockIdx.x * 256 + threadIdx.x;
  if (i >= n8) return;
  const f4* src = (const f4*)x;
  f4 a = src[2 * i];
  f4 b = src[2 * i + 1];
  us8 o;
  o[0] = f2bf(a[0]); o[1] = f2bf(a[1]); o[2] = f2bf(a[2]); o[3] = f2bf(a[3]);
  o[4] = f2bf(b[0]); o[5] = f2bf(b[1]); o[6] = f2bf(b[2]); o[7] = f2bf(b[3]);
  xb[i] = o;
}

// W_q arrives as int32 per element; int8-range values are exact in bf16.
__global__ void __launch_bounds__(256) cvt_w_kernel(const int* __restrict__ w,
                                                    us8* __restrict__ wb, int n16) {
  int i = blockIdx.x * 256 + threadIdx.x;
  if (i >= n16) return;
  const i4* src = (const i4*)w + 4 * (size_t)i;
  i4 v0 = src[0], v1 = src[1], v2 = src[2], v3 = src[3];
  us8 lo, hi;
  lo[0] = f2bf((float)v0[0]); lo[1] = f2bf((float)v0[1]);
  lo[2] = f2bf((float)v0[2]); lo[3] = f2bf((float)v0[3]);
  lo[4] = f2bf((float)v1[0]); lo[5] = f2bf((float)v1[1]);
  lo[6] = f2bf((float)v1[2]); lo[7] = f2bf((float)v1[3]);
  hi[0] = f2bf((float)v2[0]); hi[1] = f2bf((float)v2[1]);
  hi[2] = f2bf((float)v2[2]); hi[3] = f2bf((float)v2[3]);
  hi[4] = f2bf((float)v3[0]); hi[5] = f2bf((float)v3[1]);
  hi[6] = f2bf((float)v3[2]); hi[7] = f2bf((float)v3[3]);
  wb[2 * (size_t)i] = lo;
  wb[2 * (size_t)i + 1] = hi;
}

// ---------------- deep-pipelined GEMM (T1+T2+T4+T5) ----------------
// 128x256 tile, BK=64, 8 waves (2m x 4n), wave tile 64x64 (B-cols strided wn*16+j*64).
// LDS: 2 bufs x {A[128][64], B0[128][64], B1[128][64]} = 96 KiB.
// Per K-tile: phase A (reads A+B0, computes j=0,1) + phase B (reads B1, computes j=2,3).
// Stage slots: t.phA stages B1 of t+1 (buf d^1); t.phB stages A,B0 of t+2 (buf d).
// Region safety: each region's last read completes >=1 trailing barrier before its re-stage.
// vmcnt ledger (2 loads/region): steady outstanding at wait = 6 -> vmcnt(6); tail 2/0.
// LDS swizzle: byte ^= (row&7)<<4 both on staging source (inverse) and ds_read.

#define STAGE2(g0, g1, dst)        \
  do {                             \
    gload_lds16((g0), (dst));      \
    gload_lds16((g1), (dst) + 8192); \
  } while (0)

__global__ void __launch_bounds__(512, 2) gemm_pipe(
    const unsigned short* __restrict__ Xb,   // [M, K] bf16
    const unsigned short* __restrict__ Wb,   // [N, K] bf16
    const float* __restrict__ scale,         // [N]
    const float* __restrict__ bias,          // [N]
    float* __restrict__ out) {               // [M, N] fp32
  __shared__ __align__(16) char lds[2 * 3 * 16384];  // 96 KiB

  const int tid = threadIdx.x;
  const int lane = tid & 63;
  const int wid = tid >> 6;   // 0..7
  const int wm = wid >> 2;    // 0..1
  const int wn = wid & 3;     // 0..3
  const int fr = lane & 15;
  const int fq = lane >> 4;

  // T1: XCD-aware swizzle (688 % 8 == 0 -> bijective). Consecutive wg share bn.
  const int bid = blockIdx.x;
  const int wg = (bid & 7) * (GRID / 8) + (bid >> 3);
  const int bm = wg & 15;
  const int bn = wg >> 4;

  // staging source: thread covers (row = tid>>3 [+64 for j=1], col16 = (tid&7)^(row&7))
  const int srow = tid >> 3;
  const int scol = ((tid & 7) ^ (srow & 7)) * 8;  // elements
  const unsigned short* gA0 = Xb + (size_t)(bm * BM + srow) * K_DIM + scol;
  const unsigned short* gA1 = gA0 + (size_t)64 * K_DIM;
  const unsigned short* gB00 = Wb + (size_t)(bn * BN + srow) * K_DIM + scol;
  const unsigned short* gB01 = gB00 + (size_t)64 * K_DIM;
  const unsigned short* gB10 = Wb + (size_t)(bn * BN + 128 + srow) * K_DIM + scol;
  const unsigned short* gB11 = gB10 + (size_t)64 * K_DIM;

  // ds_read offsets (region-local, swizzled). row&7 == lane&7 for all frags.
  const int swz = (lane & 7) << 4;
  const int ck0 = (fq * 16) ^ swz;         // kk=0
  const int ck1 = (64 + fq * 16) ^ swz;    // kk=1
  const int arow = (wm * 64 + fr) * 128;   // + m*2048
  const int brow = (wn * 16 + fr) * 128;   // + j*8192

  // ---- prologue: stage tiles 0 (buf0) and 1 (buf1), order A,B0,B1 each
  {
    char* b0 = lds;
    STAGE2(gA0, gA1, b0 + 0 + wid * 1024);
    STAGE2(gB00, gB01, b0 + 16384 + wid * 1024);
    STAGE2(gB10, gB11, b0 + 32768 + wid * 1024);
    char* b1 = lds + 49152;
    STAGE2(gA0 + BK, gA1 + BK, b1 + 0 + wid * 1024);
    STAGE2(gB00 + BK, gB01 + BK, b1 + 16384 + wid * 1024);
    STAGE2(gB10 + BK, gB11 + BK, b1 + 32768 + wid * 1024);
  }
  VMCNT6();   // tile 0's 6 loads retired
  BARRIER();

  f32x4 acc[4][4] = {};

  for (int t = 0; t < NT; ++t) {
    const int d = t & 1;
    const char* buf = lds + d * 49152;
    const int koff = t * BK;

    // ---------- PHASE A ----------
    bf16x8 a[4][2], p0[2][2];
#pragma unroll
    for (int m = 0; m < 4; ++m) {
      a[m][0] = *(const bf16x8*)(buf + arow + m * 2048 + ck0);
      a[m][1] = *(const bf16x8*)(buf + arow + m * 2048 + ck1);
    }
#pragma unroll
    for (int j = 0; j < 2; ++j) {
      p0[j][0] = *(const bf16x8*)(buf + 16384 + brow + j * 8192 + ck0);
      p0[j][1] = *(const bf16x8*)(buf + 16384 + brow + j * 8192 + ck1);
    }
    if (t >= 1 && t + 1 < NT) {  // stage B1 of tile t+1 into buf d^1 (freed after t-1.phB)
      char* dst = lds + (d ^ 1) * 49152 + 32768 + wid * 1024;
      STAGE2(gB10 + koff + BK, gB11 + koff + BK, dst);
    }
    if (t <= NT - 2) { VMCNT6(); } else { VMCNT0(); }
    BARRIER();
    __builtin_amdgcn_s_setprio(1);
#pragma unroll
    for (int m = 0; m < 4; ++m)
#pragma unroll
      for (int j = 0; j < 2; ++j) {
        acc[m][j] = __builtin_amdgcn_mfma_f32_16x16x32_bf16(a[m][0], p0[j][0], acc[m][j], 0, 0, 0);
        acc[m][j] = __builtin_amdgcn_mfma_f32_16x16x32_bf16(a[m][1], p0[j][1], acc[m][j], 0, 0, 0);
      }
    __builtin_amdgcn_s_setprio(0);
    BARRIER();

    // ---------- PHASE B ----------
    bf16x8 p1[2][2];
#pragma unroll
    for (int j = 0; j < 2; ++j) {
      p1[j][0] = *(const bf16x8*)(buf + 32768 + brow + j * 8192 + ck0);
      p1[j][1] = *(const bf16x8*)(buf + 32768 + brow + j * 8192 + ck1);
    }
    if (t + 2 < NT) {  // stage A,B0 of tile t+2 into buf d (freed after t.phA)
      char* dbase = lds + d * 49152;
      const int ko2 = koff + 2 * BK;
      STAGE2(gA0 + ko2, gA1 + ko2, dbase + 0 + wid * 1024);
      STAGE2(gB00 + ko2, gB01 + ko2, dbase + 16384 + wid * 1024);
    }
    if (t <= NT - 3) { VMCNT6(); } else if (t == NT - 2) { VMCNT2(); } else { VMCNT0(); }
    BARRIER();
    __builtin_amdgcn_s_setprio(1);
#pragma unroll
    for (int m = 0; m < 4; ++m)
#pragma unroll
      for (int j = 0; j < 2; ++j) {
        acc[m][2 + j] = __builtin_amdgcn_mfma_f32_16x16x32_bf16(a[m][0], p1[j][0], acc[m][2 + j], 0, 0, 0);
        acc[m][2 + j] = __builtin_amdgcn_mfma_f32_16x16x32_bf16(a[m][1], p1[j][1], acc[m][2 + j], 0, 0, 0);
      }
    __builtin_amdgcn_s_setprio(0);
    BARRIER();
  }

  // ---- epilogue: C/D layout col=lane&15, row=(lane>>4)*4+jj; scale/bias in fp32
#pragma unroll
  for (int j = 0; j < 4; ++j) {
    const int c = bn * BN + wn * 16 + j * 64 + fr;
    const float sc = scale[c];
    const float bi = bias[c];
#pragma unroll
    for (int m = 0; m < 4; ++m) {
      const int r0 = bm * BM + wm * 64 + m * 16 + fq * 4;
#pragma unroll
      for (int jj = 0; jj < 4; ++jj)
        out[(size_t)(r0 + jj) * N_DIM + c] = acc[m][j][jj] * sc + bi;
    }
  }
}

// ---------------- fallback (only if d_ws too small) ----------------

__global__ void __launch_bounds__(256) naive_kernel(
    const float* __restrict__ x, const int* __restrict__ w,
    const float* __restrict__ scale, const float* __restrict__ bias,
    float* __restrict__ out) {
  size_t idx = (size_t)blockIdx.x * 256 + threadIdx.x;
  if (idx >= (size_t)M_DIM * N_DIM) return;
  int m = (int)(idx / N_DIM);
  int n = (int)(idx % N_DIM);
  const float* xr = x + (size_t)m * K_DIM;
  const int* wr = w + (size_t)n * K_DIM;
  float acc = 0.f;
  for (int k = 0; k < K_DIM; k += 4) {
    f4 xv = *(const f4*)(xr + k);
    i4 wv = *(const i4*)(wr + k);
    acc += xv[0] * (float)wv[0];
    acc += xv[1] * (float)wv[1];
    acc += xv[2] * (float)wv[2];
    acc += xv[3] * (float)wv[3];
  }
  out[idx] = acc * scale[n] + bias[n];
}

// ---------------- launch ----------------

extern "C" void kernel_launch(void* const* d_in, const int* in_sizes, int n_in,
                              void* d_out, int out_size, void* d_ws, size_t ws_size,
                              hipStream_t stream) {
  const float* x = (const float*)d_in[0];
  const int* wq = (const int*)d_in[1];
  const float* scale = (const float*)d_in[2];
  const float* bias = (const float*)d_in[3];
  float* out = (float*)d_out;

  const size_t xb_bytes = (size_t)M_DIM * K_DIM * 2;   // 16.8 MB
  const size_t wb_bytes = (size_t)N_DIM * K_DIM * 2;   // 90.2 MB

  if (ws_size >= xb_bytes + wb_bytes) {
    unsigned short* xb = (unsigned short*)d_ws;
    unsigned short* wb = (unsigned short*)((char*)d_ws + xb_bytes);

    const int n8 = M_DIM * K_DIM / 8;
    cvt_x_kernel<<<(n8 + 255) / 256, 256, 0, stream>>>(x, (us8*)xb, n8);

    const int n16 = N_DIM * K_DIM / 16;
    cvt_w_kernel<<<(n16 + 255) / 256, 256, 0, stream>>>(wq, (us8*)wb, n16);

    gemm_pipe<<<GRID, 512, 0, stream>>>(xb, wb, scale, bias, out);
  } else {
    const size_t total = (size_t)M_DIM * N_DIM;
    naive_kernel<<<(unsigned)((total + 255) / 256), 256, 0, stream>>>(x, wq, scale, bias, out);
  }
}